// Round 11
// baseline (5519.934 us; speedup 1.0000x reference)
//
#include <hip/hip_runtime.h>
#include <hip/hip_bf16.h>

typedef __hip_bfloat16 hbf16;
typedef __attribute__((ext_vector_type(8))) short bfrag8;
typedef __attribute__((ext_vector_type(4))) short short4v;
typedef __attribute__((ext_vector_type(4))) float f32x4;

#define BATCH 16
#define HH 512
#define WW 512
#define HWSZ (HH * WW)
#define TIL 24          // output tile (24x24)
#define NTB 22          // ceil(512/24)

__device__ __forceinline__ short f2bf(float f) {
    hbf16 h = __float2bfloat16(f);
    return *(short*)&h;
}

// ---------------------------------------------------------------------------
// Block-wide sum reduction (256 threads = 4 waves of 64)
// ---------------------------------------------------------------------------
__device__ __forceinline__ float blockSum(float v) {
#pragma unroll
    for (int o = 32; o > 0; o >>= 1) v += __shfl_down(v, o, 64);
    __shared__ float sh[4];
    const int lane = threadIdx.x & 63, wid = threadIdx.x >> 6;
    if (lane == 0) sh[wid] = v;
    __syncthreads();
    float r = 0.f;
    if (threadIdx.x == 0) r = sh[0] + sh[1] + sh[2] + sh[3];
    __syncthreads();
    return r;
}

// ---------------------------------------------------------------------------
// One 16->16 conv layer, LDS in -> LDS out (ping-pong, no aliasing).
// Buffers addressed with their ALLOCATION extent/stride (inAE/inAS etc.);
// logical output extent SOUT <= allocation. hal = output halo vs tile origin.
// MFMA mapping identical to the HW-verified R6/R7 kernels:
//   K = koff*16+ci ; A row=lane&15 (cout) ; B col=lane&15 (pixel) ;
//   C/D col=lane&15, row=(lane>>4)*4+i.
// ---------------------------------------------------------------------------
__device__ __forceinline__ void conv_mid(
    const short* __restrict__ inb, int inAE, int inAS,
    short* __restrict__ outb, int outAE, int outAS, int SOUT, int hal,
    const float* __restrict__ w, const float* __restrict__ bias,
    int lane, int wv, int ty0, int tx0)
{
    const int arow = lane & 15, grp = lane >> 4, lx = lane & 15;
    const int half = grp & 1, cib = half * 8, kofb = grp >> 1;
    bfrag8 af[5];
#pragma unroll
    for (int s = 0; s < 5; ++s) {
        const int koff = 2 * s + kofb;
#pragma unroll
        for (int j = 0; j < 8; ++j)
            af[s][j] = (koff < 9) ? f2bf(w[(arow * 16 + cib + j) * 9 + koff])
                                  : (short)0;
    }
    const int c0 = grp * 4;
    const float bi0 = bias[c0], bi1 = bias[c0 + 1],
                bi2 = bias[c0 + 2], bi3 = bias[c0 + 3];
    const int ho = c0 >> 3, co = c0 & 7;

    for (int y = wv; y < SOUT; y += 8) {
        f32x4 a0 = { bi0, bi1, bi2, bi3 }, a1 = a0;
#pragma unroll
        for (int s = 0; s < 5; ++s) {
            int koff = 2 * s + kofb;
            if (koff > 8) koff = 8;           // pad tap (A is zero)
            const int dy = koff / 3, dx = koff - dy * 3;
            const int rowb = (half * inAE + (y + dy)) * inAS;
            const bfrag8 b0 = *(const bfrag8*)&inb[(rowb + lx + dx) * 8];
            const int x1 = min(16 + lx, SOUT - 1) + dx;
            const bfrag8 b1 = *(const bfrag8*)&inb[(rowb + x1) * 8];
            a0 = __builtin_amdgcn_mfma_f32_16x16x32_bf16(af[s], b0, a0, 0, 0, 0);
            a1 = __builtin_amdgcn_mfma_f32_16x16x32_bf16(af[s], b1, a1, 0, 0, 0);
        }
        const int gy = ty0 - hal + y;
        const f32x4 ac[2] = { a0, a1 };
#pragma unroll
        for (int c = 0; c < 2; ++c) {
            const int xr = c * 16 + lx;
            if (xr < SOUT) {
                const int gx = tx0 - hal + xr;
                const bool inim = ((unsigned)gy < (unsigned)HH) &&
                                  ((unsigned)gx < (unsigned)WW);
                short4v st;
#pragma unroll
                for (int i = 0; i < 4; ++i) {
                    float r = ac[c][i];
                    r = (r >= 0.f) ? r : 0.01f * r;
                    st[i] = inim ? f2bf(r) : (short)0;
                }
                *(short4v*)&outb[((ho * outAE + y) * outAS + xr) * 8 + co] = st;
            }
        }
    }
}

// ---------------------------------------------------------------------------
// Kernel A: layers w0..w3. Stage 2 fp32 planes (32x32 halo tile) -> L0 ->
// L1 -> L2 -> L3 -> global act4 (NHWC bf16). LDS 59.8 KB -> 2 blocks/CU.
// ---------------------------------------------------------------------------
__global__ __launch_bounds__(512, 4) void k_predA(
    const float* __restrict__ p0, long long s0,
    const float* __restrict__ p1, long long s1,
    short* __restrict__ actG,
    const float* __restrict__ w0, const float* __restrict__ b0,
    const float* __restrict__ w1, const float* __restrict__ b1,
    const float* __restrict__ w2, const float* __restrict__ b2,
    const float* __restrict__ w3, const float* __restrict__ b3)
{
    __shared__ short fin[2 * 32 * 32];        //  4,096 B
    __shared__ short buf1[2 * 30 * 31 * 8];   // 29,760 B
    __shared__ short buf2[2 * 28 * 29 * 8];   // 25,984 B

    const int tid = threadIdx.x, lane = tid & 63, wv = tid >> 6;
    const int tx0 = blockIdx.x * TIL, ty0 = blockIdx.y * TIL;
    const long long b = blockIdx.z;

    // stage input planes, 32x32, origin -4, zero-pad
    const float* pa = p0 + b * s0;
    const float* pb = p1 + b * s1;
    for (int idx = tid; idx < 2 * 32 * 32; idx += 512) {
        const int ci = idx >> 10, r = idx & 1023, yy = r >> 5, xx = r & 31;
        const int gy = ty0 - 4 + yy, gx = tx0 - 4 + xx;
        float v = 0.f;
        if ((unsigned)gy < (unsigned)HH && (unsigned)gx < (unsigned)WW)
            v = (ci ? pb : pa)[gy * WW + gx];
        fin[idx] = f2bf(v);
    }

    // L0 A-frag: K=18 (k = tap*2 + ci), padded to 32
    const int arow = lane & 15, grp = lane >> 4, lx = lane & 15;
    bfrag8 a0f;
#pragma unroll
    for (int j = 0; j < 8; ++j) {
        const int k = grp * 8 + j;
        a0f[j] = (k < 18) ? f2bf(w0[arow * 18 + (k & 1) * 9 + (k >> 1)])
                          : (short)0;
    }
    const int c0 = grp * 4;
    const float fb0 = b0[c0], fb1 = b0[c0 + 1], fb2 = b0[c0 + 2], fb3 = b0[c0 + 3];
    const int ho = c0 >> 3, co = c0 & 7;

    __syncthreads();

    // L0: fin -> buf1 (S=30, hal=3)
    for (int y = wv; y < 30; y += 8) {
        f32x4 ac[2];
        ac[0] = f32x4{ fb0, fb1, fb2, fb3 }; ac[1] = ac[0];
#pragma unroll
        for (int c = 0; c < 2; ++c) {
            const int xc = (c == 0) ? lx : min(16 + lx, 29);
            bfrag8 bf;
#pragma unroll
            for (int j = 0; j < 8; ++j) {
                const int k = grp * 8 + j;
                short v = 0;
                if (k < 18) {
                    const int tap = k >> 1, dy = tap / 3, dx = tap - dy * 3;
                    v = fin[(k & 1) * 1024 + (y + dy) * 32 + (xc + dx)];
                }
                bf[j] = v;
            }
            ac[c] = __builtin_amdgcn_mfma_f32_16x16x32_bf16(a0f, bf, ac[c], 0, 0, 0);
        }
        const int gy = ty0 - 3 + y;
#pragma unroll
        for (int c = 0; c < 2; ++c) {
            const int xr = c * 16 + lx;
            if (xr < 30) {
                const int gx = tx0 - 3 + xr;
                const bool inim = ((unsigned)gy < (unsigned)HH) &&
                                  ((unsigned)gx < (unsigned)WW);
                short4v st;
#pragma unroll
                for (int i = 0; i < 4; ++i) {
                    float r = ac[c][i];
                    r = (r >= 0.f) ? r : 0.01f * r;
                    st[i] = inim ? f2bf(r) : (short)0;
                }
                *(short4v*)&buf1[((ho * 30 + y) * 31 + xr) * 8 + co] = st;
            }
        }
    }
    __syncthreads();

    conv_mid(buf1, 30, 31, buf2, 28, 29, 28, 2, w1, b1, lane, wv, ty0, tx0);
    __syncthreads();
    conv_mid(buf2, 28, 29, buf1, 30, 31, 26, 1, w2, b2, lane, wv, ty0, tx0);
    __syncthreads();

    // L3: buf1 (extent 26 stored in AE30/AS31) -> global act4 (S=24, hal=0)
    {
        const int half = grp & 1, cib = half * 8, kofb = grp >> 1;
        bfrag8 af[5];
#pragma unroll
        for (int s = 0; s < 5; ++s) {
            const int koff = 2 * s + kofb;
#pragma unroll
            for (int j = 0; j < 8; ++j)
                af[s][j] = (koff < 9) ? f2bf(w3[(arow * 16 + cib + j) * 9 + koff])
                                      : (short)0;
        }
        const float bi0 = b3[c0], bi1 = b3[c0 + 1],
                    bi2 = b3[c0 + 2], bi3 = b3[c0 + 3];
        for (int y = wv; y < 24; y += 8) {
            f32x4 a0 = { bi0, bi1, bi2, bi3 }, a1 = a0;
#pragma unroll
            for (int s = 0; s < 5; ++s) {
                int koff = 2 * s + kofb;
                if (koff > 8) koff = 8;
                const int dy = koff / 3, dx = koff - dy * 3;
                const int rowb = (half * 30 + (y + dy)) * 31;
                const bfrag8 q0 = *(const bfrag8*)&buf1[(rowb + lx + dx) * 8];
                const int x1 = min(16 + lx, 23) + dx;
                const bfrag8 q1 = *(const bfrag8*)&buf1[(rowb + x1) * 8];
                a0 = __builtin_amdgcn_mfma_f32_16x16x32_bf16(af[s], q0, a0, 0, 0, 0);
                a1 = __builtin_amdgcn_mfma_f32_16x16x32_bf16(af[s], q1, a1, 0, 0, 0);
            }
            const int gy = ty0 + y;
            const f32x4 ac2[2] = { a0, a1 };
#pragma unroll
            for (int c = 0; c < 2; ++c) {
                const int xr = c * 16 + lx;
                const int gx = tx0 + xr;
                if (xr < 24 && gy < HH && gx < WW) {
                    short4v st;
#pragma unroll
                    for (int i = 0; i < 4; ++i) {
                        float r = ac2[c][i];
                        r = (r >= 0.f) ? r : 0.01f * r;
                        st[i] = f2bf(r);
                    }
                    *(short4v*)&actG[((b * HWSZ + (long long)gy * WW + gx) * 16 + c0)] = st;
                }
            }
        }
    }
}

// ---------------------------------------------------------------------------
// Kernel B: layers w4..w7. Stage act4 (32x32 halo tile, NHWC bf16) ->
// L4 -> L5 -> L6 -> L7 + clip + median3 + (xsrc - med) -> plane.
// LDS 63.6 KB -> 2 blocks/CU.
// ---------------------------------------------------------------------------
__global__ __launch_bounds__(512, 4) void k_predB(
    const short* __restrict__ actG,
    const float* __restrict__ xsrc, long long xstride,
    float* __restrict__ outp,
    const float* __restrict__ w4, const float* __restrict__ b4,
    const float* __restrict__ w5, const float* __restrict__ b5,
    const float* __restrict__ w6, const float* __restrict__ b6,
    const float* __restrict__ w7, const float* __restrict__ b7)
{
    __shared__ short bufS[2 * 32 * 33 * 8];   // 33,792 B
    __shared__ short bufT[2 * 30 * 31 * 8];   // 29,760 B

    const int tid = threadIdx.x, lane = tid & 63, wv = tid >> 6;
    const int tx0 = blockIdx.x * TIL, ty0 = blockIdx.y * TIL;
    const long long b = blockIdx.z;

    // stage act4 tile 32x32, origin -4, zero-pad, NHWC granules
    for (int idx = tid; idx < 2 * 32 * 32; idx += 512) {
        const int half = idx & 1, pix = idx >> 1;
        const int yy = pix >> 5, xx = pix & 31;
        const int gy = ty0 - 4 + yy, gx = tx0 - 4 + xx;
        bfrag8 v = {0, 0, 0, 0, 0, 0, 0, 0};
        if ((unsigned)gy < (unsigned)HH && (unsigned)gx < (unsigned)WW)
            v = *(const bfrag8*)&actG[((b * HWSZ + (long long)gy * WW + gx) * 16 + half * 8)];
        *(bfrag8*)&bufS[((half * 32 + yy) * 33 + xx) * 8] = v;
    }
    __syncthreads();

    conv_mid(bufS, 32, 33, bufT, 30, 31, 30, 3, w4, b4, lane, wv, ty0, tx0);
    __syncthreads();
    conv_mid(bufT, 30, 31, bufS, 32, 33, 28, 2, w5, b5, lane, wv, ty0, tx0);
    __syncthreads();
    conv_mid(bufS, 32, 33, bufT, 30, 31, 26, 1, w6, b6, lane, wv, ty0, tx0);
    __syncthreads();

    // L7: bufT (extent 26 in AE30/AS31) -> clip/median3/subtract -> outp
    const int arow = lane & 15, grp = lane >> 4, lx = lane & 15;
    const int half = grp & 1, cib = half * 8, kofb = grp >> 1;
    bfrag8 lf[5];
#pragma unroll
    for (int s = 0; s < 5; ++s) {
        const int koff = 2 * s + kofb;
#pragma unroll
        for (int j = 0; j < 8; ++j)
            lf[s][j] = (arow < 3 && koff < 9)
                         ? f2bf(w7[(arow * 16 + cib + j) * 9 + koff]) : (short)0;
    }
    const float lb0 = (grp == 0) ? b7[0] : 0.f;
    const float lb1 = (grp == 0) ? b7[1] : 0.f;
    const float lb2 = (grp == 0) ? b7[2] : 0.f;
    const float* xb = xsrc + b * xstride;
    float* ob = outp + b * (long long)HWSZ;

    for (int y = wv; y < 24; y += 8) {
        f32x4 a0 = { lb0, lb1, lb2, 0.f }, a1 = a0;
#pragma unroll
        for (int s = 0; s < 5; ++s) {
            int koff = 2 * s + kofb;
            if (koff > 8) koff = 8;
            const int dy = koff / 3, dx = koff - dy * 3;
            const int rowb = (half * 30 + (y + dy)) * 31;
            const bfrag8 q0 = *(const bfrag8*)&bufT[(rowb + lx + dx) * 8];
            const int x1 = min(16 + lx, 23) + dx;
            const bfrag8 q1 = *(const bfrag8*)&bufT[(rowb + x1) * 8];
            a0 = __builtin_amdgcn_mfma_f32_16x16x32_bf16(lf[s], q0, a0, 0, 0, 0);
            a1 = __builtin_amdgcn_mfma_f32_16x16x32_bf16(lf[s], q1, a1, 0, 0, 0);
        }
        if (grp == 0) {
            const int gy = ty0 + y;
            const f32x4 pr[2] = { a0, a1 };
#pragma unroll
            for (int c = 0; c < 2; ++c) {
                const int x = c * 16 + lx;
                const int gx = tx0 + x;
                if (x < 24 && gy < HH && gx < WW) {
                    float y0 = fminf(fmaxf(pr[c][0], -1.f), 1.f);
                    float y1 = fminf(fmaxf(pr[c][1], -1.f), 1.f);
                    float y2 = fminf(fmaxf(pr[c][2], -1.f), 1.f);
                    float med = fmaxf(fminf(y0, fmaxf(y1, y2)), fminf(y1, y2));
                    const long long pix = (long long)gy * WW + gx;
                    ob[pix] = xb[pix] - med;
                }
            }
        }
    }
}

// ---------------------------------------------------------------------------
// Stats over x: sum of squares + per-(b,c) 256-bin histogram
// ---------------------------------------------------------------------------
__global__ __launch_bounds__(256) void k_stats_x(
    const float* __restrict__ x, unsigned* __restrict__ hist, float* __restrict__ sums)
{
    const int p = blockIdx.y;
    const float* src = x + (long long)p * HWSZ;
    __shared__ unsigned h[256];
    h[threadIdx.x] = 0;
    __syncthreads();

    float ss = 0.f;
    for (int i = blockIdx.x * 256 + threadIdx.x; i < HWSZ; i += gridDim.x * 256) {
        float v = src[i];
        ss += v * v;
        if (v >= -1.f && v <= 1.f) {
            int idx = (int)floorf((v + 1.f) * 128.f);
            idx = min(max(idx, 0), 255);
            atomicAdd(&h[idx], 1u);
        }
    }
    __syncthreads();
    if (h[threadIdx.x]) atomicAdd(&hist[p * 256 + threadIdx.x], h[threadIdx.x]);

    float bs = blockSum(ss);
    if (threadIdx.x == 0) atomicAdd(&sums[0], bs);
}

// ---------------------------------------------------------------------------
// Stats over deltas of one plane: delta = v - clampgrad_pred
// ---------------------------------------------------------------------------
__global__ __launch_bounds__(256) void k_stats_delta(
    const float* __restrict__ plane, int c,
    unsigned* __restrict__ hist, float* __restrict__ sums)
{
    const int b = blockIdx.y;
    const float* P = plane + (long long)b * HWSZ;
    const int row = b * 3 + c;
    __shared__ unsigned h[256];
    h[threadIdx.x] = 0;
    __syncthreads();

    float ss = 0.f;
    for (int i = blockIdx.x * 256 + threadIdx.x; i < HWSZ; i += gridDim.x * 256) {
        const int y = i >> 9, x = i & (WW - 1);
        float v = P[i];
        float n  = y ? P[i - WW] : 0.f;
        float wv = x ? P[i - 1] : 0.f;
        float nw = (y && x) ? P[i - WW - 1] : 0.f;
        float pr = n + wv - nw;
        pr = fminf(fmaxf(pr, fminf(n, wv)), fmaxf(n, wv));
        float d = v - pr;
        ss += d * d;
        if (d >= -1.f && d <= 1.f) {
            int idx = (int)floorf((d + 1.f) * 128.f);
            idx = min(max(idx, 0), 255);
            atomicAdd(&h[idx], 1u);
        }
    }
    __syncthreads();
    if (h[threadIdx.x]) atomicAdd(&hist[row * 256 + threadIdx.x], h[threadIdx.x]);

    float bs = blockSum(ss);
    if (threadIdx.x == 0) atomicAdd(&sums[1], bs);
}

// ---------------------------------------------------------------------------
// Finalize: entropies + the 4 output scalars
// ---------------------------------------------------------------------------
__global__ __launch_bounds__(256) void k_finalize(
    const unsigned* __restrict__ hist0, const unsigned* __restrict__ hist1,
    const float* __restrict__ sums, float* __restrict__ out)
{
    float e0 = 0.f, e1 = 0.f;
    for (int i = threadIdx.x; i < 48 * 256; i += 256) {
        float p0 = (float)hist0[i] * (1.0f / HWSZ);
        if (p0 > 0.f) e0 -= p0 * log2f(p0);
        float p1 = (float)hist1[i] * (1.0f / HWSZ);
        if (p1 > 0.f) e1 -= p1 * log2f(p1);
    }
    float t0 = blockSum(e0);
    float t1 = blockSum(e1);
    if (threadIdx.x == 0) {
        const float N = (float)BATCH * 3.f * (float)HWSZ;
        out[0] = 128.f * sqrtf(sums[1] / N);   // loss1 (deltas)
        out[1] = 128.f * sqrtf(sums[0] / N);   // loss0 (x)
        out[2] = t0 * (1.f / (8.f * 48.f));    // invcr0
        out[3] = t1 * (1.f / (8.f * 48.f));    // invcr1
    }
}

// ---------------------------------------------------------------------------
extern "C" void kernel_launch(void* const* d_in, const int* in_sizes, int n_in,
                              void* d_out, int out_size, void* d_ws, size_t ws_size,
                              hipStream_t stream) {
    const float* x = (const float*)d_in[0];
    const float* w[8];
    const float* bs[8];
    for (int i = 0; i < 8; ++i) {
        w[i]  = (const float*)d_in[1 + 2 * i];
        bs[i] = (const float*)d_in[2 + 2 * i];
    }

    // Workspace: planes (50.3 MB) + hists + sums + act4 global (134 MB).
    // (R7 profile proved ws_size >= 588 MB: chunk=16 ran with 2x134MB bufs.)
    char* ws = (char*)d_ws;
    size_t o = 0;
    float* rpl = (float*)(ws + o); o += (size_t)BATCH * HWSZ * 4;
    float* gpl = (float*)(ws + o); o += (size_t)BATCH * HWSZ * 4;
    float* bpl = (float*)(ws + o); o += (size_t)BATCH * HWSZ * 4;
    unsigned* hist0 = (unsigned*)(ws + o); o += 48 * 256 * 4;
    unsigned* hist1 = (unsigned*)(ws + o); o += 48 * 256 * 4;
    float* sums = (float*)(ws + o); o += 256;
    short* actG = (short*)(ws + o); o += (size_t)BATCH * HWSZ * 16 * 2;

    hipMemsetAsync(hist0, 0, 48 * 256 * 4 * 2 + 256, stream);

    const dim3 fgrid(NTB, NTB, BATCH);

    auto predictor = [&](const float* pa, long long sa, const float* pb, long long sb,
                         const float* xs, float* outp) {
        k_predA<<<fgrid, 512, 0, stream>>>(pa, sa, pb, sb, actG,
                                           w[0], bs[0], w[1], bs[1],
                                           w[2], bs[2], w[3], bs[3]);
        k_predB<<<fgrid, 512, 0, stream>>>(actG, xs, 3LL * HWSZ, outp,
                                           w[4], bs[4], w[5], bs[5],
                                           w[6], bs[6], w[7], bs[7]);
    };

    // r = x_r - pred(g, b);  g = x_g - pred(r, b);  b = x_b - pred(r, g)
    predictor(x + 1LL * HWSZ, 3LL * HWSZ, x + 2LL * HWSZ, 3LL * HWSZ,
              x + 0LL * HWSZ, rpl);
    predictor(rpl, (long long)HWSZ, x + 2LL * HWSZ, 3LL * HWSZ,
              x + 1LL * HWSZ, gpl);
    predictor(rpl, (long long)HWSZ, gpl, (long long)HWSZ,
              x + 2LL * HWSZ, bpl);

    const dim3 sgrid(64, 48);
    k_stats_x<<<sgrid, 256, 0, stream>>>(x, hist0, sums);
    const dim3 dgrid(64, BATCH);
    k_stats_delta<<<dgrid, 256, 0, stream>>>(rpl, 0, hist1, sums);
    k_stats_delta<<<dgrid, 256, 0, stream>>>(gpl, 1, hist1, sums);
    k_stats_delta<<<dgrid, 256, 0, stream>>>(bpl, 2, hist1, sums);

    k_finalize<<<1, 256, 0, stream>>>(hist0, hist1, sums, (float*)d_out);
}

// Round 13
// 3560.397 us; speedup vs baseline: 1.5504x; 1.5504x over previous
//
#include <hip/hip_runtime.h>
#include <hip/hip_bf16.h>

typedef __hip_bfloat16 hbf16;
typedef __attribute__((ext_vector_type(8))) short bfrag8;
typedef __attribute__((ext_vector_type(4))) short short4v;
typedef __attribute__((ext_vector_type(4))) float f32x4;

#define BATCH 16
#define HH 512
#define WW 512
#define HWSZ (HH * WW)

// pair-fusion tile geometry: 32x16 output, 2 layers, halo 2
#define PTX 32
#define PTY 16
#define IROWS 20
#define ICOLS 36
#define ISTR 37
#define MROWS 18
#define MCOLS 34
#define MSTR 35

__device__ __forceinline__ short f2bf(float f) {
    hbf16 h = __float2bfloat16(f);
    return *(short*)&h;
}

__device__ __forceinline__ float blockSum(float v) {
#pragma unroll
    for (int o = 32; o > 0; o >>= 1) v += __shfl_down(v, o, 64);
    __shared__ float sh[4];
    const int lane = threadIdx.x & 63, wid = threadIdx.x >> 6;
    if (lane == 0) sh[wid] = v;
    __syncthreads();
    float r = 0.f;
    if (threadIdx.x == 0) r = sh[0] + sh[1] + sh[2] + sh[3];
    __syncthreads();
    return r;
}

// ---------------------------------------------------------------------------
// Layer 0 via MFMA: K=18 (k=tap*2+ci) fits one 16x16x32 k-step.
// Tile 64x8, grid (8,64,zc). Writes act NHWC bf16.
// ---------------------------------------------------------------------------
__global__ __launch_bounds__(256) void k_conv_first_mfma(
    const float* __restrict__ p0, long long s0,
    const float* __restrict__ p1, long long s1,
    short* __restrict__ out,
    const float* __restrict__ w0, const float* __restrict__ b0)
{
    __shared__ short sIn[2 * 10 * 67];
    const int tid = threadIdx.x, lane = tid & 63, wvd = tid >> 6;
    const int tx0 = blockIdx.x * 64, ty0 = blockIdx.y * 8;
    const long long b = blockIdx.z;

    const float* pa = p0 + b * s0;
    const float* pb = p1 + b * s1;
    for (int idx = tid; idx < 2 * 10 * 66; idx += 256) {
        const int ci = idx / 660, rem = idx - ci * 660;
        const int yy = rem / 66, xx = rem - yy * 66;
        const int gy = ty0 - 1 + yy, gx = tx0 - 1 + xx;
        float v = 0.f;
        if ((unsigned)gy < (unsigned)HH && (unsigned)gx < (unsigned)WW)
            v = (ci ? pb : pa)[gy * WW + gx];
        sIn[(ci * 10 + yy) * 67 + xx] = f2bf(v);
    }

    const int arow = lane & 15, grp = lane >> 4, lx = lane & 15;
    bfrag8 a0f;
#pragma unroll
    for (int j = 0; j < 8; ++j) {
        const int k = grp * 8 + j;
        a0f[j] = (k < 18) ? f2bf(w0[arow * 18 + (k & 1) * 9 + (k >> 1)])
                          : (short)0;
    }
    const int c0 = grp * 4;
    const float bi0 = b0[c0], bi1 = b0[c0 + 1], bi2 = b0[c0 + 2], bi3 = b0[c0 + 3];
    __syncthreads();

    const int pxl = wvd * 16 + lx;
    for (int y = 0; y < 8; ++y) {
        bfrag8 bf;
#pragma unroll
        for (int j = 0; j < 8; ++j) {
            const int k = grp * 8 + j;
            short v = 0;
            if (k < 18) {
                const int tap = k >> 1, dy = tap / 3, dx = tap - dy * 3;
                v = sIn[((k & 1) * 10 + y + dy) * 67 + (pxl + dx)];
            }
            bf[j] = v;
        }
        f32x4 ac = { bi0, bi1, bi2, bi3 };
        ac = __builtin_amdgcn_mfma_f32_16x16x32_bf16(a0f, bf, ac, 0, 0, 0);
        short4v st;
#pragma unroll
        for (int i = 0; i < 4; ++i) {
            float r = ac[i];
            st[i] = f2bf(r >= 0.f ? r : 0.01f * r);
        }
        *(short4v*)&out[((b * HWSZ + (long long)(ty0 + y) * WW + tx0 + pxl) * 16 + c0)] = st;
    }
}

// ---------------------------------------------------------------------------
// TWO fused conv16 layers: global NHWC in -> LDS -> LDS -> global NHWC out.
// 32x16 output tile; in 20x36 (halo 2), mid 18x34 (halo 1). LDS 43.8 KB ->
// 3 blocks/CU. MFMA mapping = HW-verified R6/R7 kernels.
// ---------------------------------------------------------------------------
__global__ __launch_bounds__(256) void k_conv16_pair(
    const short* __restrict__ in, short* __restrict__ out,
    const float* __restrict__ wa, const float* __restrict__ ba,
    const float* __restrict__ wb, const float* __restrict__ bb)
{
    __shared__ short bufI[2 * IROWS * ISTR * 8];
    __shared__ short bufM[2 * MROWS * MSTR * 8];
    const int tid = threadIdx.x, lane = tid & 63, wv = tid >> 6;
    const int tx0 = blockIdx.x * PTX, ty0 = blockIdx.y * PTY;
    const long long b = blockIdx.z;

    // stage in-tile (origin -2), NHWC granules, zero-pad
    for (int idx = tid; idx < 2 * IROWS * ICOLS; idx += 256) {
        const int half = idx & 1, pix = idx >> 1;
        const int yy = pix / ICOLS, xx = pix - yy * ICOLS;
        const int gy = ty0 - 2 + yy, gx = tx0 - 2 + xx;
        bfrag8 v = {0, 0, 0, 0, 0, 0, 0, 0};
        if ((unsigned)gy < (unsigned)HH && (unsigned)gx < (unsigned)WW)
            v = *(const bfrag8*)&in[((b * HWSZ + (long long)gy * WW + gx) * 16 + half * 8)];
        *(bfrag8*)&bufI[((half * IROWS + yy) * ISTR + xx) * 8] = v;
    }

    const int arow = lane & 15, grp = lane >> 4, lx = lane & 15;
    const int half = grp & 1, cib = half * 8, kofb = grp >> 1;
    const int c0 = grp * 4, ho = c0 >> 3, co = c0 & 7;

    bfrag8 afA[5];
#pragma unroll
    for (int s = 0; s < 5; ++s) {
        const int koff = 2 * s + kofb;
#pragma unroll
        for (int j = 0; j < 8; ++j)
            afA[s][j] = (koff < 9) ? f2bf(wa[(arow * 16 + cib + j) * 9 + koff])
                                   : (short)0;
    }
    const float ba0 = ba[c0], ba1 = ba[c0 + 1], ba2 = ba[c0 + 2], ba3 = ba[c0 + 3];
    __syncthreads();

    // Layer A: bufI -> bufM (18 rows x 34 cols, origin -1)
    for (int y = wv; y < MROWS; y += 4) {
        f32x4 a0 = { ba0, ba1, ba2, ba3 }, a1 = a0, a2 = a0;
#pragma unroll
        for (int s = 0; s < 5; ++s) {
            int koff = 2 * s + kofb;
            if (koff > 8) koff = 8;
            const int dy = koff / 3, dx = koff - dy * 3;
            const int row = (half * IROWS + y + dy) * ISTR;
            const bfrag8 q0 = *(const bfrag8*)&bufI[(row + lx + dx) * 8];
            const bfrag8 q1 = *(const bfrag8*)&bufI[(row + 16 + lx + dx) * 8];
            const int x2 = min(32 + lx, MCOLS - 1) + dx;
            const bfrag8 q2 = *(const bfrag8*)&bufI[(row + x2) * 8];
            a0 = __builtin_amdgcn_mfma_f32_16x16x32_bf16(afA[s], q0, a0, 0, 0, 0);
            a1 = __builtin_amdgcn_mfma_f32_16x16x32_bf16(afA[s], q1, a1, 0, 0, 0);
            a2 = __builtin_amdgcn_mfma_f32_16x16x32_bf16(afA[s], q2, a2, 0, 0, 0);
        }
        const int gy = ty0 - 1 + y;
        const f32x4 ac[3] = { a0, a1, a2 };
#pragma unroll
        for (int c = 0; c < 3; ++c) {
            const int xr = c * 16 + lx;
            if (xr < MCOLS) {
                const int gx = tx0 - 1 + xr;
                const bool inim = ((unsigned)gy < (unsigned)HH) &&
                                  ((unsigned)gx < (unsigned)WW);
                short4v st;
#pragma unroll
                for (int i = 0; i < 4; ++i) {
                    float r = ac[c][i];
                    r = (r >= 0.f) ? r : 0.01f * r;
                    st[i] = inim ? f2bf(r) : (short)0;
                }
                *(short4v*)&bufM[((ho * MROWS + y) * MSTR + xr) * 8 + co] = st;
            }
        }
    }

    bfrag8 afB[5];
#pragma unroll
    for (int s = 0; s < 5; ++s) {
        const int koff = 2 * s + kofb;
#pragma unroll
        for (int j = 0; j < 8; ++j)
            afB[s][j] = (koff < 9) ? f2bf(wb[(arow * 16 + cib + j) * 9 + koff])
                                   : (short)0;
    }
    const float bb0 = bb[c0], bb1 = bb[c0 + 1], bb2 = bb[c0 + 2], bb3 = bb[c0 + 3];
    __syncthreads();

    // Layer B: bufM -> global (16 rows x 32 cols, origin 0)
    for (int y = wv; y < PTY; y += 4) {
        f32x4 a0 = { bb0, bb1, bb2, bb3 }, a1 = a0;
#pragma unroll
        for (int s = 0; s < 5; ++s) {
            int koff = 2 * s + kofb;
            if (koff > 8) koff = 8;
            const int dy = koff / 3, dx = koff - dy * 3;
            const int row = (half * MROWS + y + dy) * MSTR;
            const bfrag8 q0 = *(const bfrag8*)&bufM[(row + lx + dx) * 8];
            const bfrag8 q1 = *(const bfrag8*)&bufM[(row + 16 + lx + dx) * 8];
            a0 = __builtin_amdgcn_mfma_f32_16x16x32_bf16(afB[s], q0, a0, 0, 0, 0);
            a1 = __builtin_amdgcn_mfma_f32_16x16x32_bf16(afB[s], q1, a1, 0, 0, 0);
        }
        const f32x4 ac[2] = { a0, a1 };
#pragma unroll
        for (int c = 0; c < 2; ++c) {
            const int xr = c * 16 + lx;
            short4v st;
#pragma unroll
            for (int i = 0; i < 4; ++i) {
                float r = ac[c][i];
                st[i] = f2bf(r >= 0.f ? r : 0.01f * r);
            }
            *(short4v*)&out[((b * HWSZ + (long long)(ty0 + y) * WW + tx0 + xr) * 16 + c0)] = st;
        }
    }
}

// ---------------------------------------------------------------------------
// Last layer via MFMA (R7 verbatim): act NHWC -> clip+median3+(x - med).
// ---------------------------------------------------------------------------
__global__ __launch_bounds__(256) void k_conv_last_mfma(
    const short* __restrict__ in,
    const float* __restrict__ xsrc, long long xstride,
    float* __restrict__ outp,
    const float* __restrict__ w, const float* __restrict__ bias)
{
    __shared__ short s_tile[2 * 10 * 66 * 8];
    const int tid = threadIdx.x;
    const int lane = tid & 63, wvid = tid >> 6;
    const int bx0 = blockIdx.x * 64, by0 = blockIdx.y * 8;
    const short* inb = in + (long long)blockIdx.z * 16 * HWSZ;

    for (int idx = tid; idx < 10 * 66 * 2; idx += 256) {
        const int half = idx & 1, pix = idx >> 1;
        const int yy = pix / 66, xx = pix - yy * 66;
        const int gy = by0 + yy - 1, gx = bx0 + xx - 1;
        bfrag8 v = {0, 0, 0, 0, 0, 0, 0, 0};
        if ((unsigned)gy < (unsigned)HH && (unsigned)gx < (unsigned)WW)
            v = *(const bfrag8*)(inb + ((long long)gy * WW + gx) * 16 + half * 8);
        *(bfrag8*)&s_tile[((half * 10 + yy) * 66 + xx) * 8] = v;
    }

    const int arow = lane & 15;
    const int grp  = lane >> 4;
    const int half = grp & 1;
    const int cib  = half * 8;
    const int kofb = grp >> 1;
    bfrag8 lf[5];
#pragma unroll
    for (int s = 0; s < 5; ++s) {
        const int koff = 2 * s + kofb;
#pragma unroll
        for (int j = 0; j < 8; ++j)
            lf[s][j] = (arow < 3 && koff < 9)
                         ? f2bf(w[(arow * 16 + cib + j) * 9 + koff]) : (short)0;
    }
    const float bi0 = (grp == 0) ? bias[0] : 0.f;
    const float bi1 = (grp == 0) ? bias[1] : 0.f;
    const float bi2 = (grp == 0) ? bias[2] : 0.f;

    __syncthreads();

    const int pxl = wvid * 16 + (lane & 15);
    const int gx = bx0 + pxl;
    const float* xb = xsrc + (long long)blockIdx.z * xstride;
    float* ob = outp + (long long)blockIdx.z * HWSZ;

    for (int yy = 0; yy < 8; ++yy) {
        f32x4 acc = { bi0, bi1, bi2, 0.f };
#pragma unroll
        for (int s = 0; s < 5; ++s) {
            int koff = 2 * s + kofb;
            if (koff > 8) koff = 8;
            const int dy = koff / 3, dx = koff - dy * 3;
            const bfrag8 bfr = *(const bfrag8*)&s_tile[((half * 10 + yy + dy) * 66 + pxl + dx) * 8];
            acc = __builtin_amdgcn_mfma_f32_16x16x32_bf16(lf[s], bfr, acc, 0, 0, 0);
        }
        if (grp == 0) {
            float y0 = fminf(fmaxf(acc[0], -1.f), 1.f);
            float y1 = fminf(fmaxf(acc[1], -1.f), 1.f);
            float y2 = fminf(fmaxf(acc[2], -1.f), 1.f);
            float med = fmaxf(fminf(y0, fmaxf(y1, y2)), fminf(y1, y2));
            const long long pix = (long long)(by0 + yy) * WW + gx;
            ob[pix] = xb[pix] - med;
        }
    }
}

// ---------------------------------------------------------------------------
// Stats over x: float4 loads, per-wave LDS histograms, SSQ
// ---------------------------------------------------------------------------
__global__ __launch_bounds__(256) void k_stats_x(
    const float* __restrict__ x, unsigned* __restrict__ hist, float* __restrict__ sums)
{
    const int p = blockIdx.y;
    const f32x4* src = (const f32x4*)(x + (long long)p * HWSZ);
    __shared__ unsigned h[4][256];
    for (int i = threadIdx.x; i < 1024; i += 256) ((unsigned*)h)[i] = 0;
    __syncthreads();
    const int wid = threadIdx.x >> 6;

    float ss = 0.f;
    for (int i4 = blockIdx.x * 256 + threadIdx.x; i4 < HWSZ / 4; i4 += gridDim.x * 256) {
        const f32x4 v4 = src[i4];
#pragma unroll
        for (int e = 0; e < 4; ++e) {
            const float v = v4[e];
            ss += v * v;
            if (v >= -1.f && v <= 1.f) {
                int idx = (int)floorf((v + 1.f) * 128.f);
                idx = min(max(idx, 0), 255);
                atomicAdd(&h[wid][idx], 1u);
            }
        }
    }
    __syncthreads();
    const unsigned t = h[0][threadIdx.x] + h[1][threadIdx.x] +
                       h[2][threadIdx.x] + h[3][threadIdx.x];
    if (t) atomicAdd(&hist[p * 256 + threadIdx.x], t);

    float bs = blockSum(ss);
    if (threadIdx.x == 0) atomicAdd(&sums[0], bs);
}

// ---------------------------------------------------------------------------
// Stats over deltas, all 3 planes in one dispatch (z = channel).
// delta = v - clampgrad_pred; float4 loads; per-wave LDS histograms.
// ---------------------------------------------------------------------------
__global__ __launch_bounds__(256) void k_stats_delta(
    const float* __restrict__ planes,
    unsigned* __restrict__ hist, float* __restrict__ sums)
{
    const int b = blockIdx.y, cz = blockIdx.z;
    const float* P = planes + ((long long)cz * BATCH + b) * HWSZ;
    const int row = b * 3 + cz;
    __shared__ unsigned h[4][256];
    for (int i = threadIdx.x; i < 1024; i += 256) ((unsigned*)h)[i] = 0;
    __syncthreads();
    const int wid = threadIdx.x >> 6;

    float ss = 0.f;
    for (int i4 = blockIdx.x * 256 + threadIdx.x; i4 < HWSZ / 4; i4 += gridDim.x * 256) {
        const int i0 = i4 * 4;
        const int y = i0 >> 9, x0 = i0 & (WW - 1);
        const f32x4 cur = ((const f32x4*)P)[i4];
        f32x4 up = { 0.f, 0.f, 0.f, 0.f };
        if (y) up = ((const f32x4*)P)[i4 - (WW / 4)];
        const float left = x0 ? P[i0 - 1] : 0.f;
        const float upl = (x0 && y) ? P[i0 - WW - 1] : 0.f;
#pragma unroll
        for (int e = 0; e < 4; ++e) {
            const float v = cur[e];
            const float n = up[e];
            const float wv = e ? cur[e - 1] : left;
            const float nw = e ? up[e - 1] : upl;
            float pr = n + wv - nw;
            pr = fminf(fmaxf(pr, fminf(n, wv)), fmaxf(n, wv));
            const float d = v - pr;
            ss += d * d;
            if (d >= -1.f && d <= 1.f) {
                int idx = (int)floorf((d + 1.f) * 128.f);
                idx = min(max(idx, 0), 255);
                atomicAdd(&h[wid][idx], 1u);
            }
        }
    }
    __syncthreads();
    const unsigned t = h[0][threadIdx.x] + h[1][threadIdx.x] +
                       h[2][threadIdx.x] + h[3][threadIdx.x];
    if (t) atomicAdd(&hist[row * 256 + threadIdx.x], t);

    float bs = blockSum(ss);
    if (threadIdx.x == 0) atomicAdd(&sums[1], bs);
}

// ---------------------------------------------------------------------------
// Finalize: entropies + the 4 output scalars
// ---------------------------------------------------------------------------
__global__ __launch_bounds__(256) void k_finalize(
    const unsigned* __restrict__ hist0, const unsigned* __restrict__ hist1,
    const float* __restrict__ sums, float* __restrict__ out)
{
    float e0 = 0.f, e1 = 0.f;
    for (int i = threadIdx.x; i < 48 * 256; i += 256) {
        float p0 = (float)hist0[i] * (1.0f / HWSZ);
        if (p0 > 0.f) e0 -= p0 * log2f(p0);
        float p1 = (float)hist1[i] * (1.0f / HWSZ);
        if (p1 > 0.f) e1 -= p1 * log2f(p1);
    }
    float t0 = blockSum(e0);
    float t1 = blockSum(e1);
    if (threadIdx.x == 0) {
        const float N = (float)BATCH * 3.f * (float)HWSZ;
        out[0] = 128.f * sqrtf(sums[1] / N);   // loss1 (deltas)
        out[1] = 128.f * sqrtf(sums[0] / N);   // loss0 (x)
        out[2] = t0 * (1.f / (8.f * 48.f));    // invcr0
        out[3] = t1 * (1.f / (8.f * 48.f));    // invcr1
    }
}

// ---------------------------------------------------------------------------
extern "C" void kernel_launch(void* const* d_in, const int* in_sizes, int n_in,
                              void* d_out, int out_size, void* d_ws, size_t ws_size,
                              hipStream_t stream) {
    const float* x = (const float*)d_in[0];
    const float* w[8];
    const float* bs[8];
    for (int i = 0; i < 8; ++i) {
        w[i]  = (const float*)d_in[1 + 2 * i];
        bs[i] = (const float*)d_in[2 + 2 * i];
    }

    // Fixed region: planes (50.33 MB, contiguous rpl/gpl/bpl) + hists + sums.
    // Activation ping-pong sized adaptively: ws_size = 256 MiB (inferred from
    // R7's WRITE_SIZE=96 MiB = 12 batches) -> chunk = 12.
    char* ws = (char*)d_ws;
    size_t o = 0;
    float* rpl = (float*)(ws + o); o += (size_t)BATCH * HWSZ * 4;
    float* gpl = (float*)(ws + o); o += (size_t)BATCH * HWSZ * 4;
    float* bpl = (float*)(ws + o); o += (size_t)BATCH * HWSZ * 4;
    unsigned* hist0 = (unsigned*)(ws + o); o += 48 * 256 * 4;
    unsigned* hist1 = (unsigned*)(ws + o); o += 48 * 256 * 4;
    float* sums = (float*)(ws + o); o += 256;

    const size_t actElems = (size_t)16 * HWSZ;          // shorts per batch
    const size_t perBatchBytes = 2 * actElems * 2;      // A+B buffers
    int chunk = 1;
    if (ws_size > o) {
        size_t c = (ws_size - o) / perBatchBytes;
        chunk = (c < 1) ? 1 : (c > BATCH ? BATCH : (int)c);
    }
    short* actA = (short*)(ws + o);
    short* actB = actA + (size_t)chunk * actElems;

    hipMemsetAsync(hist0, 0, 48 * 256 * 4 * 2 + 256, stream);

    auto predictor = [&](const float* pa, long long sa, const float* pb, long long sb,
                         const float* xs, float* outp) {
        for (int b0 = 0; b0 < BATCH; b0 += chunk) {
            const int zc = (BATCH - b0 < chunk) ? (BATCH - b0) : chunk;
            const dim3 g1(WW / 64, HH / 8, zc);
            const dim3 gp(WW / PTX, HH / PTY, zc);
            k_conv_first_mfma<<<g1, 256, 0, stream>>>(
                pa + (long long)b0 * sa, sa, pb + (long long)b0 * sb, sb,
                actA, w[0], bs[0]);
            k_conv16_pair<<<gp, 256, 0, stream>>>(actA, actB, w[1], bs[1], w[2], bs[2]);
            k_conv16_pair<<<gp, 256, 0, stream>>>(actB, actA, w[3], bs[3], w[4], bs[4]);
            k_conv16_pair<<<gp, 256, 0, stream>>>(actA, actB, w[5], bs[5], w[6], bs[6]);
            k_conv_last_mfma<<<g1, 256, 0, stream>>>(
                actB, xs + (long long)b0 * 3 * HWSZ, 3LL * HWSZ,
                outp + (long long)b0 * HWSZ, w[7], bs[7]);
        }
    };

    // r = x_r - pred(g, b);  g = x_g - pred(r, b);  b = x_b - pred(r, g)
    predictor(x + 1LL * HWSZ, 3LL * HWSZ, x + 2LL * HWSZ, 3LL * HWSZ,
              x + 0LL * HWSZ, rpl);
    predictor(rpl, (long long)HWSZ, x + 2LL * HWSZ, 3LL * HWSZ,
              x + 1LL * HWSZ, gpl);
    predictor(rpl, (long long)HWSZ, gpl, (long long)HWSZ,
              x + 2LL * HWSZ, bpl);

    const dim3 sgrid(64, 48);
    k_stats_x<<<sgrid, 256, 0, stream>>>(x, hist0, sums);
    const dim3 dgrid(64, BATCH, 3);
    k_stats_delta<<<dgrid, 256, 0, stream>>>(rpl, hist1, sums);

    k_finalize<<<1, 256, 0, stream>>>(hist0, hist1, sums, (float*)d_out);
}